// Round 6
// baseline (340.761 us; speedup 1.0000x reference)
//
#include <hip/hip_runtime.h>
#include <hip/hip_bf16.h>

// SCM_39676907888322: sigmoid-gated cross attention. fp32 I/O, bf16 MFMA compute.
// R6: attn barrier-free m-split: 4 waves/block share 32 Q-rows, each wave owns a
//     576-wide m-slice, K/V frags straight from L2 (XCD-pinned), P wave-private,
//     partials combined via LDS at end. 1152 blocks x 4 waves = 4608 waves.

typedef __bf16 bf16;
typedef __bf16 bf16x8 __attribute__((ext_vector_type(8)));
typedef __bf16 bf16x4 __attribute__((ext_vector_type(4)));
typedef float f32x4 __attribute__((ext_vector_type(4)));
typedef float f32x16 __attribute__((ext_vector_type(16)));

#define NB 8
#define NC 256
#define NCI 128
#define NHW 2304
#define NT32 72    // 2304 / 32
#define PPAD 72    // P strip row stride (32 rows x 64 m)

__global__ __launch_bounds__(256) void wconv_kernel(
    const float* __restrict__ w0, const float* __restrict__ w1,
    const float* __restrict__ w2, const float* __restrict__ w3,
    const float* __restrict__ w4, const float* __restrict__ w5,
    bf16* __restrict__ dst)
{
    int idx = (blockIdx.x * 256 + threadIdx.x) * 8;   // 6*32768 total
    int m = idx >> 15;
    int off = idx & 32767;
    const float* w = (m == 0) ? w0 : (m == 1) ? w1 : (m == 2) ? w2
                   : (m == 3) ? w3 : (m == 4) ? w4 : w5;
    f32x4 a0 = *(const f32x4*)(w + off);
    f32x4 a1 = *(const f32x4*)(w + off + 4);
    bf16x8 o;
    #pragma unroll
    for (int j = 0; j < 4; ++j) { o[j] = (bf16)a0[j]; o[4 + j] = (bf16)a1[j]; }
    *(bf16x8*)(dst + idx) = o;
}

__global__ __launch_bounds__(256) void qkv_kernel(
    const float* __restrict__ x1, const float* __restrict__ x2,
    const bf16* __restrict__ wb,
    const float* __restrict__ bv1, const float* __restrict__ bk1, const float* __restrict__ bq1,
    const float* __restrict__ bv2, const float* __restrict__ bk2, const float* __restrict__ bq2,
    bf16* __restrict__ Qt, bf16* __restrict__ Kt, bf16* __restrict__ Vt,
    float* __restrict__ out)
{
    __shared__ __align__(16) bf16 Xt[32 * 264];

    int gid = blockIdx.x;
    int nt = gid % NT32;
    int s = (gid / NT32) & 1;
    int b = gid / (2 * NT32);
    int n0 = nt * 32;

    const float* x = s ? x2 : x1;
    const bf16* wv = wb + (size_t)(s * 3 + 0) * (NCI * NC);
    const bf16* wk = wb + (size_t)(s * 3 + 1) * (NCI * NC);
    const bf16* wq = wb + (size_t)(s * 3 + 2) * (NCI * NC);
    const float* bv = s ? bv2 : bv1;
    const float* bk = s ? bk2 : bk1;
    const float* bq = s ? bq2 : bq1;
    float* outy = out + (size_t)s * (NB * 384 * NHW);

    int tid = threadIdx.x;
    {
        int noff = (tid & 7) * 4;
        int cbase = tid >> 3;
        #pragma unroll
        for (int i = 0; i < 8; ++i) {
            int c = cbase + i * 32;
            const float* src = x + ((size_t)(b * NC + c) * NHW + n0 + noff);
            f32x4 a = *(const f32x4*)src;
            *(f32x4*)(outy + ((size_t)(b * 384 + c) * NHW + n0 + noff)) = a;
            #pragma unroll
            for (int j = 0; j < 4; ++j)
                Xt[(noff + j) * 264 + c] = (bf16)a[j];
        }
    }
    __syncthreads();

    int lane = tid & 63;
    int wid = tid >> 6;
    int row = lane & 15, quad = lane >> 4;
    int ci_base = wid * 32;

    f32x4 acc[3][2][2];
    #pragma unroll
    for (int t = 0; t < 3; ++t)
        #pragma unroll
        for (int mi = 0; mi < 2; ++mi)
            #pragma unroll
            for (int j = 0; j < 2; ++j)
                acc[t][mi][j] = (f32x4){0.f, 0.f, 0.f, 0.f};

    const bf16* wptr[3] = {wq, wk, wv};
    #pragma unroll
    for (int ks = 0; ks < 8; ++ks) {
        int c0 = ks * 32 + quad * 8;
        bf16x8 bfrag[2];
        #pragma unroll
        for (int j = 0; j < 2; ++j)
            bfrag[j] = *(const bf16x8*)&Xt[(j * 16 + row) * 264 + c0];
        #pragma unroll
        for (int t = 0; t < 3; ++t) {
            #pragma unroll
            for (int mi = 0; mi < 2; ++mi) {
                bf16x8 afrag = *(const bf16x8*)&wptr[t][(size_t)(ci_base + mi * 16 + row) * NC + c0];
                #pragma unroll
                for (int j = 0; j < 2; ++j)
                    acc[t][mi][j] = __builtin_amdgcn_mfma_f32_16x16x32_bf16(
                        afrag, bfrag[j], acc[t][mi][j], 0, 0, 0);
            }
        }
    }

    size_t qkbase = ((size_t)s * NB + b) * NHW * NCI;
    size_t vbase  = ((size_t)s * NB + b) * NCI * NHW;
    #pragma unroll
    for (int mi = 0; mi < 2; ++mi) {
        int ci0 = ci_base + mi * 16 + quad * 4;
        f32x4 bq4 = *(const f32x4*)&bq[ci0];
        f32x4 bk4 = *(const f32x4*)&bk[ci0];
        f32x4 bv4 = *(const f32x4*)&bv[ci0];
        #pragma unroll
        for (int j = 0; j < 2; ++j) {
            int n = n0 + j * 16 + row;
            bf16x4 pk;
            #pragma unroll
            for (int r = 0; r < 4; ++r) pk[r] = (bf16)(acc[0][mi][j][r] + bq4[r]);
            *(bf16x4*)&Qt[qkbase + (size_t)n * NCI + ci0] = pk;
            #pragma unroll
            for (int r = 0; r < 4; ++r) pk[r] = (bf16)(acc[1][mi][j][r] + bk4[r]);
            *(bf16x4*)&Kt[qkbase + (size_t)n * NCI + ci0] = pk;
            #pragma unroll
            for (int r = 0; r < 4; ++r)
                Vt[vbase + (size_t)(ci0 + r) * NHW + n] = (bf16)(acc[2][mi][j][r] + bv4[r]);
        }
    }
}

__global__ __launch_bounds__(256, 3) void attn_kernel(
    const bf16* __restrict__ Qt, const bf16* __restrict__ Kt, const bf16* __restrict__ Vt,
    float* __restrict__ out)
{
    // 32 KB buffer: during the loop it holds 4 wave-private P strips (8 KB slots);
    // after the loop it is the partial-O combine buffer.
    __shared__ __align__(16) float CB[8192];

    int gid = blockIdx.x;
    // XCD pinning: b = gid&7 -> all of batch b's Q/K/V (~3.5 MB) in one XCD L2.
    int b = gid & 7;
    int r = gid >> 3;          // 0..143
    int dir = r & 1;
    int nt = r >> 1;           // 0..71
    int n0 = nt * 32;

    int tid = threadIdx.x;     // 256 thr, 4 waves
    int lane = tid & 63, w = tid >> 6;
    int l32 = lane & 31, h = lane >> 5;

    const bf16* q = Qt + ((size_t)dir * NB + b) * (NHW * NCI);
    const bf16* k = Kt + ((size_t)(dir ^ 1) * NB + b) * (NHW * NCI);
    const bf16* v = Vt + ((size_t)(dir ^ 1) * NB + b) * (NCI * NHW);
    float* outy = out + (size_t)dir * (NB * 384 * NHW) + ((size_t)b * 384 + 256) * NHW;

    bf16* Pw = (bf16*)CB + w * 4096;   // 8 KB slot per wave; strip uses 32*72*2 = 4.6 KB

    // Q A-frags for the block's 32 rows (same for all 4 waves), resident.
    bf16x8 qf[8];
    #pragma unroll
    for (int ks = 0; ks < 8; ++ks)
        qf[ks] = *(const bf16x8*)&q[(size_t)(n0 + l32) * NCI + ks * 16 + h * 8];

    f32x16 o[4];               // partial O: 32 rows x 128 c over this wave's m-slice
    #pragma unroll
    for (int ct = 0; ct < 4; ++ct)
        #pragma unroll
        for (int e = 0; e < 16; ++e) o[ct][e] = 0.f;

    int mbase = w * 576;       // wave-private m-slice: 9 tiles of 64
    for (int mt = 0; mt < 9; ++mt) {
        int m0 = mbase + mt * 64;
        // S = Q K^T : 32 Q-rows x 64 K-rows (K frags from L2)
        f32x16 sacc[2];
        #pragma unroll
        for (int j32 = 0; j32 < 2; ++j32)
            #pragma unroll
            for (int e = 0; e < 16; ++e) sacc[j32][e] = 0.f;
        #pragma unroll
        for (int ks = 0; ks < 8; ++ks) {
            #pragma unroll
            for (int j32 = 0; j32 < 2; ++j32) {
                bf16x8 kf = *(const bf16x8*)&k[(size_t)(m0 + j32 * 32 + l32) * NCI + ks * 16 + h * 8];
                sacc[j32] = __builtin_amdgcn_mfma_f32_32x32x16_bf16(qf[ks], kf, sacc[j32], 0, 0, 0);
            }
        }
        // sigmoid -> P (wave-private strip; same-wave DS ordering, no barrier)
        // C/D: col=l32 (K-row), row=(reg&3)+8*(reg>>2)+4*h (Q-row).
        #pragma unroll
        for (int j32 = 0; j32 < 2; ++j32) {
            #pragma unroll
            for (int g = 0; g < 4; ++g) {
                #pragma unroll
                for (int e = 0; e < 4; ++e) {
                    float xv = sacc[j32][g * 4 + e];
                    float ex = __expf(-xv);
                    float p = __builtin_amdgcn_rcpf(1.0f + ex);
                    Pw[(e + 8 * g + 4 * h) * PPAD + j32 * 32 + l32] = (bf16)p;
                }
            }
        }
        // O += P V^T : A = P from LDS, B = V frags from L2
        #pragma unroll
        for (int ks2 = 0; ks2 < 4; ++ks2) {
            bf16x8 af = *(const bf16x8*)&Pw[l32 * PPAD + ks2 * 16 + h * 8];
            #pragma unroll
            for (int ct = 0; ct < 4; ++ct) {
                bf16x8 vf = *(const bf16x8*)&v[(size_t)(ct * 32 + l32) * NHW + m0 + ks2 * 16 + h * 8];
                o[ct] = __builtin_amdgcn_mfma_f32_32x32x16_bf16(af, vf, o[ct], 0, 0, 0);
            }
        }
    }

    // ---- Combine the 4 waves' partials via LDS (chunk-major: conflict-free) ----
    __syncthreads();
    if (w >= 2) {              // phase 1: waves 2,3 dump full partials (16 KB each)
        float* dst = CB + (w - 2) * 4096;
        #pragma unroll
        for (int ct = 0; ct < 4; ++ct)
            #pragma unroll
            for (int g = 0; g < 4; ++g) {
                f32x4 pk;
                #pragma unroll
                for (int e = 0; e < 4; ++e) pk[e] = o[ct][g * 4 + e];
                *(f32x4*)&dst[(ct * 4 + g) * 256 + lane * 4] = pk;
            }
    }
    __syncthreads();
    if (w < 2) {               // waves 0,1 absorb
        const float* src = CB + w * 4096;
        #pragma unroll
        for (int ct = 0; ct < 4; ++ct)
            #pragma unroll
            for (int g = 0; g < 4; ++g) {
                f32x4 pk = *(const f32x4*)&src[(ct * 4 + g) * 256 + lane * 4];
                #pragma unroll
                for (int e = 0; e < 4; ++e) o[ct][g * 4 + e] += pk[e];
            }
    }
    __syncthreads();
    // phase 2: cross-swap halves so wave0 finalizes ct{0,1}, wave1 finalizes ct{2,3}
    if (w == 0) {
        #pragma unroll
        for (int ct = 2; ct < 4; ++ct)
            #pragma unroll
            for (int g = 0; g < 4; ++g) {
                f32x4 pk;
                #pragma unroll
                for (int e = 0; e < 4; ++e) pk[e] = o[ct][g * 4 + e];
                *(f32x4*)&CB[((ct - 2) * 4 + g) * 256 + lane * 4] = pk;
            }
    } else if (w == 1) {
        #pragma unroll
        for (int ct = 0; ct < 2; ++ct)
            #pragma unroll
            for (int g = 0; g < 4; ++g) {
                f32x4 pk;
                #pragma unroll
                for (int e = 0; e < 4; ++e) pk[e] = o[ct][g * 4 + e];
                *(f32x4*)&CB[2048 + (ct * 4 + g) * 256 + lane * 4] = pk;
            }
    }
    __syncthreads();
    if (w == 0) {
        #pragma unroll
        for (int ct = 0; ct < 2; ++ct) {
            int c = ct * 32 + l32;
            #pragma unroll
            for (int g = 0; g < 4; ++g) {
                f32x4 pk = *(const f32x4*)&CB[2048 + (ct * 4 + g) * 256 + lane * 4];
                #pragma unroll
                for (int e = 0; e < 4; ++e) pk[e] += o[ct][g * 4 + e];
                *(f32x4*)&outy[(size_t)c * NHW + n0 + 8 * g + 4 * h] = pk;
            }
        }
    } else if (w == 1) {
        #pragma unroll
        for (int ct = 2; ct < 4; ++ct) {
            int c = ct * 32 + l32;
            #pragma unroll
            for (int g = 0; g < 4; ++g) {
                f32x4 pk = *(const f32x4*)&CB[((ct - 2) * 4 + g) * 256 + lane * 4];
                #pragma unroll
                for (int e = 0; e < 4; ++e) pk[e] += o[ct][g * 4 + e];
                *(f32x4*)&outy[(size_t)c * NHW + n0 + 8 * g + 4 * h] = pk;
            }
        }
    }
}

extern "C" void kernel_launch(void* const* d_in, const int* in_sizes, int n_in,
                              void* d_out, int out_size, void* d_ws, size_t ws_size,
                              hipStream_t stream) {
    const float* x1  = (const float*)d_in[0];
    const float* x2  = (const float*)d_in[1];
    const float* wv1 = (const float*)d_in[2];  const float* bv1 = (const float*)d_in[3];
    const float* wk1 = (const float*)d_in[4];  const float* bk1 = (const float*)d_in[5];
    const float* wq1 = (const float*)d_in[6];  const float* bq1 = (const float*)d_in[7];
    const float* wv2 = (const float*)d_in[8];  const float* bv2 = (const float*)d_in[9];
    const float* wk2 = (const float*)d_in[10]; const float* bk2 = (const float*)d_in[11];
    const float* wq2 = (const float*)d_in[12]; const float* bq2 = (const float*)d_in[13];
    float* out = (float*)d_out;

    // ws layout (bf16): Qt[2][B][2304][128] | Kt | Vt[2][B][128][2304] | wb[6][128*256]
    size_t per = (size_t)2 * NB * NHW * NCI;
    bf16* Qt = (bf16*)d_ws;
    bf16* Kt = Qt + per;
    bf16* Vt = Kt + per;
    bf16* wb = Vt + per;

    wconv_kernel<<<dim3(96), dim3(256), 0, stream>>>(wv1, wk1, wq1, wv2, wk2, wq2, wb);

    qkv_kernel<<<dim3(NB * 2 * NT32), dim3(256), 0, stream>>>(
        x1, x2, wb, bv1, bk1, bq1, bv2, bk2, bq2, Qt, Kt, Vt, out);

    attn_kernel<<<dim3(NB * 2 * NT32), dim3(256), 0, stream>>>(Qt, Kt, Vt, out);
}

// Round 7
// 282.036 us; speedup vs baseline: 1.2082x; 1.2082x over previous
//
#include <hip/hip_runtime.h>
#include <hip/hip_bf16.h>

// SCM_39676907888322: sigmoid-gated cross attention. fp32 I/O, bf16 MFMA compute.
// R7: everything pre-packed in MFMA fragment order -> all hot-loop global loads
//     are contiguous 1KB/wave (4 lines/inst). attn computes S^T = K*Q^T so P's
//     C/D layout converts to the PV B-operand with a lane^32 shuffle (no LDS, no
//     barriers in loop). O computed transposed (D[m=c][n=q]), coalesced stores.
//     m-split 4 ways/block, R6's proven LDS combine for partials.

typedef __bf16 bf16;
typedef __bf16 bf16x8 __attribute__((ext_vector_type(8)));
typedef __bf16 bf16x4 __attribute__((ext_vector_type(4)));
typedef float f32x4 __attribute__((ext_vector_type(4)));
typedef float f32x16 __attribute__((ext_vector_type(16)));

#define NB 8
#define NC 256
#define NCI 128
#define NHW 2304
#define NT32 72    // 2304 / 32

// wpack: [st(6)][ks(8)][ci(128)][c-chunk(32)] bf16  (st = s*3 + {0=v,1=k,2=q})
__global__ __launch_bounds__(256) void wconv_kernel(
    const float* __restrict__ w0, const float* __restrict__ w1,
    const float* __restrict__ w2, const float* __restrict__ w3,
    const float* __restrict__ w4, const float* __restrict__ w5,
    bf16* __restrict__ wp)
{
    int g = blockIdx.x * 256 + threadIdx.x;   // 24576 groups of 8
    int c8 = g & 3;                            // 8-elem chunk within 32 c
    int ci = (g >> 2) & 127;
    int stks = g >> 9;                         // 0..47
    int st = stks >> 3, ks = stks & 7;
    const float* w = (st == 0) ? w0 : (st == 1) ? w1 : (st == 2) ? w2
                   : (st == 3) ? w3 : (st == 4) ? w4 : w5;
    const float* src = w + ci * NC + ks * 32 + c8 * 8;
    f32x4 a0 = *(const f32x4*)src;
    f32x4 a1 = *(const f32x4*)(src + 4);
    bf16x8 o;
    #pragma unroll
    for (int j = 0; j < 4; ++j) { o[j] = (bf16)a0[j]; o[4 + j] = (bf16)a1[j]; }
    *(bf16x8*)(wp + (size_t)g * 8) = o;
}

// Qp/Kp: [(s*8+b)][qb/mb(72)][ks(8)][lane(64)][8]  — B/A operand order, k=ci
// Vp:    [(s*8+b)][mb(72)][ks2(2)*4+ct][lane(64)][8] — A operand order, m=c, k=m-dim
__global__ __launch_bounds__(256) void qkv_kernel(
    const float* __restrict__ x1, const float* __restrict__ x2,
    const bf16* __restrict__ wp,
    const float* __restrict__ bv1, const float* __restrict__ bk1, const float* __restrict__ bq1,
    const float* __restrict__ bv2, const float* __restrict__ bk2, const float* __restrict__ bq2,
    bf16* __restrict__ Qp, bf16* __restrict__ Kp, bf16* __restrict__ Vp,
    float* __restrict__ out)
{
    __shared__ __align__(16) bf16 Xt[32 * 264];

    int gid = blockIdx.x;
    int nt = gid % NT32;
    int s = (gid / NT32) & 1;
    int b = gid / (2 * NT32);
    int n0 = nt * 32;

    const float* x = s ? x2 : x1;
    const float* bv = s ? bv2 : bv1;
    const float* bk = s ? bk2 : bk1;
    const float* bq = s ? bq2 : bq1;
    float* outy = out + (size_t)s * (NB * 384 * NHW);

    int tid = threadIdx.x;
    {   // coalesced staging + fp32 concat passthrough
        int noff = (tid & 7) * 4;
        int cbase = tid >> 3;
        #pragma unroll
        for (int i = 0; i < 8; ++i) {
            int c = cbase + i * 32;
            const float* src = x + ((size_t)(b * NC + c) * NHW + n0 + noff);
            f32x4 a = *(const f32x4*)src;
            *(f32x4*)(outy + ((size_t)(b * 384 + c) * NHW + n0 + noff)) = a;
            #pragma unroll
            for (int j = 0; j < 4; ++j)
                Xt[(noff + j) * 264 + c] = (bf16)a[j];
        }
    }
    __syncthreads();

    int lane = tid & 63;
    int wid = tid >> 6;
    int row = lane & 15, quad = lane >> 4;

    f32x4 acc[3][2][2];                  // [t: 0=q,1=k,2=v][mi][jj]
    #pragma unroll
    for (int t = 0; t < 3; ++t)
        #pragma unroll
        for (int mi = 0; mi < 2; ++mi)
            #pragma unroll
            for (int j = 0; j < 2; ++j)
                acc[t][mi][j] = (f32x4){0.f, 0.f, 0.f, 0.f};

    // st for acc t: t=0(q)->s*3+2, t=1(k)->s*3+1, t=2(v)->s*3+0
    int stmap[3] = {s * 3 + 2, s * 3 + 1, s * 3 + 0};
    #pragma unroll
    for (int ks = 0; ks < 8; ++ks) {
        bf16x8 bfrag[2];
        int c0 = ks * 32 + quad * 8;
        #pragma unroll
        for (int j = 0; j < 2; ++j)
            bfrag[j] = *(const bf16x8*)&Xt[(j * 16 + row) * 264 + c0];
        #pragma unroll
        for (int t = 0; t < 3; ++t) {
            #pragma unroll
            for (int mi = 0; mi < 2; ++mi) {
                // packed weights: contiguous 1KB per (st,ks,wid,mi)
                const bf16* wa = wp + (((size_t)(stmap[t] * 8 + ks) * 128 + wid * 32 + mi * 16) * 32)
                               + row * 32 + quad * 8;
                bf16x8 afrag = *(const bf16x8*)wa;
                #pragma unroll
                for (int j = 0; j < 2; ++j)
                    acc[t][mi][j] = __builtin_amdgcn_mfma_f32_16x16x32_bf16(
                        afrag, bfrag[j], acc[t][mi][j], 0, 0, 0);
            }
        }
    }

    // Epilogue: +bias, write packs.
    size_t qkb = ((size_t)(s * NB + b) * 72 + nt) * 4096;   // elem offset of this mb/qb
    int eoff = (quad & 1) * 4;
    int loff = 32 * (quad >> 1);
    #pragma unroll
    for (int mi = 0; mi < 2; ++mi) {
        int ci0 = wid * 32 + mi * 16 + quad * 4;
        int ksl = wid * 2 + mi;                 // ci>>4
        f32x4 bq4 = *(const f32x4*)&bq[ci0];
        f32x4 bk4 = *(const f32x4*)&bk[ci0];
        f32x4 bv4 = *(const f32x4*)&bv[ci0];
        #pragma unroll
        for (int jj = 0; jj < 2; ++jj) {
            int moff = jj * 16 + row;           // n&31 (D col = lane&15)
            size_t qkoff = qkb + (size_t)ksl * 512 + (size_t)(moff + loff) * 8 + eoff;
            bf16x4 pk;
            #pragma unroll
            for (int r = 0; r < 4; ++r) pk[r] = (bf16)(acc[0][mi][jj][r] + bq4[r]);
            *(bf16x4*)&Qp[qkoff] = pk;
            #pragma unroll
            for (int r = 0; r < 4; ++r) pk[r] = (bf16)(acc[1][mi][jj][r] + bk4[r]);
            *(bf16x4*)&Kp[qkoff] = pk;
            // Vpack: lane = (ci&31) + 32*((row>>3)&1), elem = row&7, slot = jj*4+wid
            size_t vb = qkb + (size_t)(jj * 4 + wid) * 512
                      + (size_t)(mi * 16 + quad * 4) * 8 + (size_t)(32 * 8) * ((row >> 3) & 1)
                      + (row & 7);
            #pragma unroll
            for (int r = 0; r < 4; ++r)
                Vp[vb + r * 8] = (bf16)(acc[2][mi][jj][r] + bv4[r]);
        }
    }
}

__global__ __launch_bounds__(256, 2) void attn_kernel(
    const bf16* __restrict__ Qp, const bf16* __restrict__ Kp, const bf16* __restrict__ Vp,
    float* __restrict__ out)
{
    __shared__ __align__(16) float CB[8192];   // combine buffer (32 KB), unused in loop

    int gid = blockIdx.x;
    int b = gid & 7;                 // XCD pin
    int r0 = gid >> 3;               // 0..143
    int dir = r0 & 1;
    int qt = r0 >> 1;                // 0..71
    int n0 = qt * 32;

    int tid = threadIdx.x;
    int lane = tid & 63, w = tid >> 6;
    int l32 = lane & 31, h = lane >> 5;
    bool hb = (h != 0);

    const bf16* qb = Qp + (((size_t)(dir * NB + b) * 72 + qt) * 4096);
    const bf16* kb0 = Kp + ((size_t)((dir ^ 1) * NB + b) * 72) * 4096;
    const bf16* vb0 = Vp + ((size_t)((dir ^ 1) * NB + b) * 72) * 4096;
    float* outy = out + (size_t)dir * (NB * 384 * NHW) + ((size_t)b * 384 + 256) * NHW;

    // Q B-frags: fully coalesced (1KB/inst), resident.
    bf16x8 qf[8];
    #pragma unroll
    for (int ks = 0; ks < 8; ++ks)
        qf[ks] = *(const bf16x8*)&qb[ks * 512 + lane * 8];

    f32x16 o[4];                     // O^T partial: D[m=c(16 regs)][n=q(col)]
    #pragma unroll
    for (int ct = 0; ct < 4; ++ct)
        #pragma unroll
        for (int e = 0; e < 16; ++e) o[ct][e] = 0.f;

    union U8 { int i[4]; bf16x8 v; };

    int mb0 = w * 18;                // wave-private 18 m-blocks of 32
    for (int mb = mb0; mb < mb0 + 18; ++mb) {
        const bf16* kb = kb0 + (size_t)mb * 4096;
        const bf16* vb = vb0 + (size_t)mb * 4096;
        // S^T = K Q^T : D[m=K-row][n=q]
        f32x16 sacc;
        #pragma unroll
        for (int e = 0; e < 16; ++e) sacc[e] = 0.f;
        #pragma unroll
        for (int ks = 0; ks < 8; ++ks) {
            bf16x8 kf = *(const bf16x8*)&kb[ks * 512 + lane * 8];
            sacc = __builtin_amdgcn_mfma_f32_32x32x16_bf16(kf, qf[ks], sacc, 0, 0, 0);
        }
        // sigmoid -> bf16 quads (quad g holds m-rows {g*8+4h' .. +3} pattern)
        int2 pqi[4];
        #pragma unroll
        for (int g = 0; g < 4; ++g) {
            bf16x4 pq;
            #pragma unroll
            for (int e = 0; e < 4; ++e) {
                float xv = sacc[g * 4 + e];
                float ex = __expf(-xv);
                pq[e] = (bf16)__builtin_amdgcn_rcpf(1.0f + ex);
            }
            pqi[g] = *(int2*)&pq;
        }
        // PV: O^T += V * P^T, two k=16 steps per 32-m block.
        #pragma unroll
        for (int ks2 = 0; ks2 < 2; ++ks2) {
            int2 own  = hb ? pqi[2 * ks2 + 1] : pqi[2 * ks2];
            int2 send = hb ? pqi[2 * ks2]     : pqi[2 * ks2 + 1];
            int2 recv;
            recv.x = __shfl_xor(send.x, 32, 64);
            recv.y = __shfl_xor(send.y, 32, 64);
            int2 lo = hb ? recv : own;   // j0..3 (from h'=0 lane)
            int2 hi = hb ? own : recv;   // j4..7 (from h'=1 lane)
            U8 u; u.i[0] = lo.x; u.i[1] = lo.y; u.i[2] = hi.x; u.i[3] = hi.y;
            const bf16* vbs = vb + ks2 * 2048;
            #pragma unroll
            for (int ct = 0; ct < 4; ++ct) {
                bf16x8 vf = *(const bf16x8*)&vbs[ct * 512 + lane * 8];
                o[ct] = __builtin_amdgcn_mfma_f32_32x32x16_bf16(vf, u.v, o[ct], 0, 0, 0);
            }
        }
    }

    // ---- Combine 4 waves' partials via LDS (R6-proven structure) ----
    __syncthreads();
    if (w >= 2) {                    // waves 2,3 dump
        float* dst = CB + (w - 2) * 4096;
        #pragma unroll
        for (int ct = 0; ct < 4; ++ct)
            #pragma unroll
            for (int g = 0; g < 4; ++g) {
                f32x4 pk;
                #pragma unroll
                for (int e = 0; e < 4; ++e) pk[e] = o[ct][g * 4 + e];
                *(f32x4*)&dst[(ct * 4 + g) * 256 + lane * 4] = pk;
            }
    }
    __syncthreads();
    if (w < 2) {                     // waves 0,1 absorb
        const float* src = CB + w * 4096;
        #pragma unroll
        for (int ct = 0; ct < 4; ++ct)
            #pragma unroll
            for (int g = 0; g < 4; ++g) {
                f32x4 pk = *(const f32x4*)&src[(ct * 4 + g) * 256 + lane * 4];
                #pragma unroll
                for (int e = 0; e < 4; ++e) o[ct][g * 4 + e] += pk[e];
            }
    }
    __syncthreads();
    if (w == 0) {                    // cross-swap: w0 -> ct{2,3}, w1 -> ct{0,1}
        #pragma unroll
        for (int ct = 2; ct < 4; ++ct)
            #pragma unroll
            for (int g = 0; g < 4; ++g) {
                f32x4 pk;
                #pragma unroll
                for (int e = 0; e < 4; ++e) pk[e] = o[ct][g * 4 + e];
                *(f32x4*)&CB[((ct - 2) * 4 + g) * 256 + lane * 4] = pk;
            }
    } else if (w == 1) {
        #pragma unroll
        for (int ct = 0; ct < 2; ++ct)
            #pragma unroll
            for (int g = 0; g < 4; ++g) {
                f32x4 pk;
                #pragma unroll
                for (int e = 0; e < 4; ++e) pk[e] = o[ct][g * 4 + e];
                *(f32x4*)&CB[2048 + (ct * 4 + g) * 256 + lane * 4] = pk;
            }
    }
    __syncthreads();
    // Final stores: c = ct*32 + e + 8*g + 4*h ; n = n0 + l32 (coalesced across l32)
    if (w == 0) {
        #pragma unroll
        for (int ct = 0; ct < 2; ++ct)
            #pragma unroll
            for (int g = 0; g < 4; ++g) {
                f32x4 pk = *(const f32x4*)&CB[2048 + (ct * 4 + g) * 256 + lane * 4];
                #pragma unroll
                for (int e = 0; e < 4; ++e) {
                    int c = ct * 32 + e + 8 * g + 4 * h;
                    outy[(size_t)c * NHW + n0 + l32] = pk[e] + o[ct][g * 4 + e];
                }
            }
    } else if (w == 1) {
        #pragma unroll
        for (int ct = 2; ct < 4; ++ct)
            #pragma unroll
            for (int g = 0; g < 4; ++g) {
                f32x4 pk = *(const f32x4*)&CB[((ct - 2) * 4 + g) * 256 + lane * 4];
                #pragma unroll
                for (int e = 0; e < 4; ++e) {
                    int c = ct * 32 + e + 8 * g + 4 * h;
                    outy[(size_t)c * NHW + n0 + l32] = pk[e] + o[ct][g * 4 + e];
                }
            }
    }
}

extern "C" void kernel_launch(void* const* d_in, const int* in_sizes, int n_in,
                              void* d_out, int out_size, void* d_ws, size_t ws_size,
                              hipStream_t stream) {
    const float* x1  = (const float*)d_in[0];
    const float* x2  = (const float*)d_in[1];
    const float* wv1 = (const float*)d_in[2];  const float* bv1 = (const float*)d_in[3];
    const float* wk1 = (const float*)d_in[4];  const float* bk1 = (const float*)d_in[5];
    const float* wq1 = (const float*)d_in[6];  const float* bq1 = (const float*)d_in[7];
    const float* wv2 = (const float*)d_in[8];  const float* bv2 = (const float*)d_in[9];
    const float* wk2 = (const float*)d_in[10]; const float* bk2 = (const float*)d_in[11];
    const float* wq2 = (const float*)d_in[12]; const float* bq2 = (const float*)d_in[13];
    float* out = (float*)d_out;

    // ws (bf16): Qp | Kp | Vp (each 2*8*72*4096 = 4718592 elems) | wpack (196608)
    size_t per = (size_t)2 * NB * 72 * 4096;
    bf16* Qp = (bf16*)d_ws;
    bf16* Kp = Qp + per;
    bf16* Vp = Kp + per;
    bf16* wp = Vp + per;

    wconv_kernel<<<dim3(96), dim3(256), 0, stream>>>(wv1, wk1, wq1, wv2, wk2, wq2, wp);

    qkv_kernel<<<dim3(NB * 2 * NT32), dim3(256), 0, stream>>>(
        x1, x2, wp, bv1, bk1, bq1, bv2, bk2, bq2, Qp, Kp, Vp, out);

    attn_kernel<<<dim3(NB * 2 * NT32), dim3(256), 0, stream>>>(Qp, Kp, Vp, out);
}